// Round 7
// baseline (185.950 us; speedup 1.0000x reference)
//
#include <hip/hip_runtime.h>
#include <math.h>

// Round 19: GEMM staging pipeline depth 1 -> 2 (triple-buffered As).
// Theory: per K-step compute (~24 MFMA ~ 120cy) << staging latency
// (200-900cy L2/L3), so with a 2-buffer the whole block stalled at each
// barrier's counted-vmcnt wait. Now stage kb+2 every step: wait
// vmcnt(7) [qkv: 1 staging + 6 wf newer] / vmcnt(3) [outp: 1 + 2],
// last iter peeled with vmcnt(6)/vmcnt(2) (no new stage issued).
// Flash/cast byte-identical to R18 (43us proven; XCD swizzle kept).

typedef __bf16 bf16x8 __attribute__((ext_vector_type(8)));
typedef float  f32x4  __attribute__((ext_vector_type(4)));
typedef unsigned u32x2 __attribute__((ext_vector_type(2)));
typedef unsigned u32x4 __attribute__((ext_vector_type(4)));
typedef unsigned short ushort_t;

__device__ __forceinline__ unsigned short f2bf(float f) {
    unsigned u = __float_as_uint(f);
    u += 0x7fffu + ((u >> 16) & 1u);          // round-to-nearest-even
    return (unsigned short)(u >> 16);
}
__device__ __forceinline__ unsigned pk16(unsigned short lo, unsigned short hi) {
    return (unsigned)lo | ((unsigned)hi << 16);
}

#define GLL16(g, l)                                                                        \
    __builtin_amdgcn_global_load_lds((const __attribute__((address_space(1))) void*)(g),   \
                                     (__attribute__((address_space(3))) void*)(l), 16, 0, 0)

// ---------------------------------------------------------------------------
// cast (1D grid, 4224 blocks): bid<3072 -> x row-major bf16. Else weight
// frag-linear: tile (t,kb) holds W[t*16+c][kb*32+g*8..+7] at
// ((t*24+kb)*64 + L)*8.
// ---------------------------------------------------------------------------
__global__ __launch_bounds__(256)
void cast_all(const float* __restrict__ x,
              const float* __restrict__ w0, const float* __restrict__ w1,
              const float* __restrict__ w2, const float* __restrict__ w3,
              ushort_t* __restrict__ xb, ushort_t* __restrict__ wb0,
              ushort_t* __restrict__ wb1, ushort_t* __restrict__ wb2,
              ushort_t* __restrict__ wb3)
{
    const int bid = blockIdx.x;
    if (bid < 3072) {
        const int i = (bid * 256 + threadIdx.x) * 8;          // 8192*768 exact
        const float4 f0 = *(const float4*)(x + i);
        const float4 f1 = *(const float4*)(x + i + 4);
        ushort4 p0, p1;
        p0.x = f2bf(f0.x); p0.y = f2bf(f0.y); p0.z = f2bf(f0.z); p0.w = f2bf(f0.w);
        p1.x = f2bf(f1.x); p1.y = f2bf(f1.y); p1.z = f2bf(f1.z); p1.w = f2bf(f1.w);
        *(ushort4*)(xb + i)     = p0;
        *(ushort4*)(xb + i + 4) = p1;
        return;
    }
    const int wt = (bid - 3072) * 4 + (threadIdx.x >> 6);     // 0..4607
    const int wsel = wt / 1152, tile = wt % 1152;
    const float* s; ushort_t* d;
    switch (wsel) {
        case 0:  s = w0; d = wb0; break;
        case 1:  s = w1; d = wb1; break;
        case 2:  s = w2; d = wb2; break;
        default: s = w3; d = wb3; break;
    }
    const int t = tile / 24, kb = tile % 24;
    const int L = threadIdx.x & 63, c = L & 15, g = L >> 4;
    const float* sp = s + (size_t)(t * 16 + c) * 768 + kb * 32 + g * 8;
    const float4 f0 = *(const float4*)sp;
    const float4 f1 = *(const float4*)(sp + 4);
    ushort4 p0, p1;
    p0.x = f2bf(f0.x); p0.y = f2bf(f0.y); p0.z = f2bf(f0.z); p0.w = f2bf(f0.w);
    p1.x = f2bf(f1.x); p1.y = f2bf(f1.y); p1.z = f2bf(f1.z); p1.w = f2bf(f1.w);
    ushort_t* dp = d + ((size_t)tile * 64 + L) * 8;
    *(ushort4*)dp       = p0;
    *(ushort4*)(dp + 4) = p1;
}

// ---------------------------------------------------------------------------
// Z-fused QKV GEMM, A triple-buffered LDS, depth-2 staging pipeline.
// Block = 64m x 128n, 4 waves. W-frags direct from frag-linear global.
// ---------------------------------------------------------------------------
__global__ __launch_bounds__(256, 3)
void gemm_qkv(const ushort_t* __restrict__ xb,
              const ushort_t* __restrict__ wqb, const ushort_t* __restrict__ wkb,
              const ushort_t* __restrict__ wvb,
              const float* __restrict__ bq, const float* __restrict__ bk,
              const float* __restrict__ bv,
              ushort_t* __restrict__ Qh, ushort_t* __restrict__ Kl,
              ushort_t* __restrict__ Vl)
{
    __shared__ ushort_t smem[9216];      // As 3x2048 [0,6144) | epi scratch 4x2304
    ushort_t* As = smem;

    const int tid = threadIdx.x, L = tid & 63, wv = tid >> 6;
    const int c = L & 15, g = L >> 4;
    const int n0 = blockIdx.x * 128, m0 = blockIdx.y * 64;

    const int qs = ((tid & 3) ^ ((tid >> 3) & 3)) * 8;   // swizzled k-chunk
    const ushort_t* ap = xb + (size_t)(m0 + (tid >> 2)) * 768 + qs;
    const int sg = (g ^ ((c >> 1) & 3)) * 8;             // swizzled read col

    // frag-linear W bases: tile t = bx*8 + wv*2 + j, offset ((t*24+kb)*64+L)*8
    const size_t wbase = ((size_t)(blockIdx.x * 8 + wv * 2) * 24 * 64 + L) * 8;
    const ushort_t* wqp = wqb + wbase;
    const ushort_t* wkp = wkb + wbase;
    const ushort_t* wvp = wvb + wbase;
    // j stride = 24*64*8 = 12288 shorts; kb stride = 512 shorts

    f32x4 acc[3][4][2];
#pragma unroll
    for (int z = 0; z < 3; ++z)
#pragma unroll
        for (int i = 0; i < 4; ++i)
#pragma unroll
            for (int j = 0; j < 2; ++j) acc[z][i][j] = (f32x4){0.f, 0.f, 0.f, 0.f};

    GLL16(ap, &As[(size_t)tid * 8]);                 // stage kb=0 -> buf0
    __builtin_amdgcn_sched_barrier(0);
    GLL16(ap + 32, &As[2048 + (size_t)tid * 8]);     // stage kb=1 -> buf1
    __builtin_amdgcn_sched_barrier(0);

    bf16x8 wf[3][2];
#pragma unroll
    for (int j = 0; j < 2; ++j) {
        wf[0][j] = *(const bf16x8*)(wqp + j * 12288);
        wf[1][j] = *(const bf16x8*)(wkp + j * 12288);
        wf[2][j] = *(const bf16x8*)(wvp + j * 12288);
    }

    for (int kb = 0; kb < 23; ++kb) {
        // GLL16(kb) is oldest; newer: GLL16(kb+1) + 6 wf prefetches = 7.
        asm volatile("s_waitcnt vmcnt(7) lgkmcnt(0)" ::: "memory");
        __builtin_amdgcn_s_barrier();
        __builtin_amdgcn_sched_barrier(0);
        if (kb < 22) {
            GLL16(ap + (kb + 2) * 32,
                  &As[((kb + 2) % 3) * 2048 + (size_t)tid * 8]);
            __builtin_amdgcn_sched_barrier(0);       // keep issue order pinned
        }
        const ushort_t* Ab = &As[(kb % 3) * 2048];
        bf16x8 af[4];
#pragma unroll
        for (int i = 0; i < 4; ++i)
            af[i] = *(const bf16x8*)&Ab[(i * 16 + c) * 32 + sg];
#pragma unroll
        for (int z = 0; z < 3; ++z)
#pragma unroll
            for (int i = 0; i < 4; ++i)
#pragma unroll
                for (int j = 0; j < 2; ++j)
                    acc[z][i][j] = __builtin_amdgcn_mfma_f32_16x16x32_bf16(
                        af[i], wf[z][j], acc[z][i][j], 0, 0, 0);
        // in-place prefetch next kb's W-frags (cross the barrier)
        const int kn = kb + 1;
#pragma unroll
        for (int j = 0; j < 2; ++j) {
            wf[0][j] = *(const bf16x8*)(wqp + j * 12288 + kn * 512);
            wf[1][j] = *(const bf16x8*)(wkp + j * 12288 + kn * 512);
            wf[2][j] = *(const bf16x8*)(wvp + j * 12288 + kn * 512);
        }
    }
    {   // peeled kb=23: no new stage issued; newer than GLL16(23): 6 wf.
        asm volatile("s_waitcnt vmcnt(6) lgkmcnt(0)" ::: "memory");
        __builtin_amdgcn_s_barrier();
        __builtin_amdgcn_sched_barrier(0);
        const ushort_t* Ab = &As[(23 % 3) * 2048];
        bf16x8 af[4];
#pragma unroll
        for (int i = 0; i < 4; ++i)
            af[i] = *(const bf16x8*)&Ab[(i * 16 + c) * 32 + sg];
#pragma unroll
        for (int z = 0; z < 3; ++z)
#pragma unroll
            for (int i = 0; i < 4; ++i)
#pragma unroll
                for (int j = 0; j < 2; ++j)
                    acc[z][i][j] = __builtin_amdgcn_mfma_f32_16x16x32_bf16(
                        af[i], wf[z][j], acc[z][i][j], 0, 0, 0);
    }

    // ---------------- epilogues (per-wave private strips) ----------------
    const int b  = m0 >> 10, nb = m0 & 1023;
    const int hcol = n0 + wv * 32;
    const int h = hcol >> 6, uh = (hcol >> 5) & 1;
    const int bh = b * 12 + h;
    ushort_t* scr = smem + wv * 2304;

    float bias2[3][2];
#pragma unroll
    for (int j = 0; j < 2; ++j) {
        bias2[0][j] = bq[hcol + j * 16 + c];
        bias2[1][j] = bk[hcol + j * 16 + c];
        bias2[2][j] = bv[hcol + j * 16 + c];
    }

    __syncthreads();   // full drain: loop buffers -> scratch reuse

    // z=0: Q plain [bh][token][hd64]; token-major strip [64][36]
#pragma unroll
    for (int i = 0; i < 4; ++i)
#pragma unroll
        for (int j = 0; j < 2; ++j)
#pragma unroll
            for (int r = 0; r < 4; ++r)
                scr[(i * 16 + g * 4 + r) * 36 + j * 16 + c] =
                    f2bf(acc[0][i][j][r] + bias2[0][j]);
#pragma unroll
    for (int e = 0; e < 4; ++e) {
        const int slot = e * 64 + L;
        const int row = slot >> 2, ch = slot & 3;
        const u32x4 v = *(const u32x4*)&scr[row * 36 + ch * 8];
        *(u32x4*)&Qh[((size_t)bh * 1024 + nb + row) * 64 + uh * 32 + ch * 8] = v;
    }

    // z=1: K frag-linear; token-major strip again
#pragma unroll
    for (int i = 0; i < 4; ++i)
#pragma unroll
        for (int j = 0; j < 2; ++j)
#pragma unroll
            for (int r = 0; r < 4; ++r)
                scr[(i * 16 + g * 4 + r) * 36 + j * 16 + c] =
                    f2bf(acc[1][i][j][r] + bias2[1][j]);
#pragma unroll
    for (int tau = 0; tau < 4; ++tau) {
        const u32x4 v = *(const u32x4*)&scr[(tau * 16 + c) * 36 + g * 8];
        *(u32x4*)&Kl[(((size_t)bh * 64 + (nb >> 4) + tau) * 2 + uh) * 512
                     + (size_t)L * 8] = v;
    }

    // z=2: V frag-linear; hd-major strip [32][68]
#pragma unroll
    for (int i = 0; i < 4; ++i)
#pragma unroll
        for (int j = 0; j < 2; ++j)
#pragma unroll
            for (int r = 0; r < 4; ++r)
                scr[(j * 16 + c) * 68 + i * 16 + g * 4 + r] =
                    f2bf(acc[2][i][j][r] + bias2[2][j]);
    const int T = nb >> 6;
#pragma unroll
    for (int t = 0; t < 4; ++t) {
        const int htl = t >> 1, u = t & 1;
        const u32x4 v = *(const u32x4*)&scr[(htl * 16 + c) * 68 + u * 32 + g * 8];
        *(u32x4*)&Vl[((((size_t)bh * 4 + uh * 2 + htl) * 16 + T) * 2 + u) * 512
                     + (size_t)L * 8] = v;
    }
}

// ---------------------------------------------------------------------------
// Out-proj GEMM, A triple-buffered LDS, depth-2 staging pipeline.
// 64m x 128n, grid 6x128.
// ---------------------------------------------------------------------------
__global__ __launch_bounds__(256, 3)
void gemm_outp(const ushort_t* __restrict__ attnb, const ushort_t* __restrict__ wob,
               const float* __restrict__ bo, float* __restrict__ out)
{
    __shared__ ushort_t smem[6144];      // As 3x2048
    ushort_t* As = smem;
    const int tid = threadIdx.x, L = tid & 63, wv = tid >> 6;
    const int c = L & 15, g = L >> 4;
    const int n0 = blockIdx.x * 128, m0 = blockIdx.y * 64;
    const int qs = ((tid & 3) ^ ((tid >> 3) & 3)) * 8;
    const ushort_t* ap = attnb + (size_t)(m0 + (tid >> 2)) * 768 + qs;
    const int sg = (g ^ ((c >> 1) & 3)) * 8;

    const size_t wbase = ((size_t)(blockIdx.x * 8 + wv * 2) * 24 * 64 + L) * 8;
    const ushort_t* wop = wob + wbase;

    f32x4 acc[4][2];
#pragma unroll
    for (int i = 0; i < 4; ++i)
#pragma unroll
        for (int j = 0; j < 2; ++j) acc[i][j] = (f32x4){0.f, 0.f, 0.f, 0.f};

    GLL16(ap, &As[(size_t)tid * 8]);                 // stage kb=0 -> buf0
    __builtin_amdgcn_sched_barrier(0);
    GLL16(ap + 32, &As[2048 + (size_t)tid * 8]);     // stage kb=1 -> buf1
    __builtin_amdgcn_sched_barrier(0);

    bf16x8 wf[2];
#pragma unroll
    for (int j = 0; j < 2; ++j) wf[j] = *(const bf16x8*)(wop + j * 12288);

    for (int kb = 0; kb < 23; ++kb) {
        // GLL16(kb) oldest; newer: GLL16(kb+1) + 2 wf = 3.
        asm volatile("s_waitcnt vmcnt(3) lgkmcnt(0)" ::: "memory");
        __builtin_amdgcn_s_barrier();
        __builtin_amdgcn_sched_barrier(0);
        if (kb < 22) {
            GLL16(ap + (kb + 2) * 32,
                  &As[((kb + 2) % 3) * 2048 + (size_t)tid * 8]);
            __builtin_amdgcn_sched_barrier(0);
        }
        const ushort_t* Ab = &As[(kb % 3) * 2048];
        bf16x8 af[4];
#pragma unroll
        for (int i = 0; i < 4; ++i)
            af[i] = *(const bf16x8*)&Ab[(i * 16 + c) * 32 + sg];
#pragma unroll
        for (int i = 0; i < 4; ++i)
#pragma unroll
            for (int j = 0; j < 2; ++j)
                acc[i][j] = __builtin_amdgcn_mfma_f32_16x16x32_bf16(
                    af[i], wf[j], acc[i][j], 0, 0, 0);
        const int kn = kb + 1;
#pragma unroll
        for (int j = 0; j < 2; ++j)
            wf[j] = *(const bf16x8*)(wop + j * 12288 + kn * 512);
    }
    {   // peeled kb=23: newer than GLL16(23): 2 wf.
        asm volatile("s_waitcnt vmcnt(2) lgkmcnt(0)" ::: "memory");
        __builtin_amdgcn_s_barrier();
        __builtin_amdgcn_sched_barrier(0);
        const ushort_t* Ab = &As[(23 % 3) * 2048];
        bf16x8 af[4];
#pragma unroll
        for (int i = 0; i < 4; ++i)
            af[i] = *(const bf16x8*)&Ab[(i * 16 + c) * 32 + sg];
#pragma unroll
        for (int i = 0; i < 4; ++i)
#pragma unroll
            for (int j = 0; j < 2; ++j)
                acc[i][j] = __builtin_amdgcn_mfma_f32_16x16x32_bf16(
                    af[i], wf[j], acc[i][j], 0, 0, 0);
    }

#pragma unroll
    for (int i = 0; i < 4; ++i) {
        const int row = m0 + i * 16 + g * 4;
#pragma unroll
        for (int j = 0; j < 2; ++j) {
            const int col = n0 + wv * 32 + j * 16 + c;
            const float bsvo = bo[col];
#pragma unroll
            for (int r = 0; r < 4; ++r)
                out[(size_t)(row + r) * 768 + col] = acc[i][j][r] + bsvo;
        }
    }
}

// ---------------------------------------------------------------------------
// Flash (R12 body + XCD swizzle): S^T = K.Q^T, fixed-max softmax, 1
// wave/block, 32 q-rows, parity P-strips, in-place K prefetch, bare
// v_exp_f32. 1D grid 3072: xcd = bid&7 owns 12 complete bh -> K/V
// L2-resident per XCD. Do NOT tighten launch bounds and do NOT insert
// setprio: both spill the ~150-reg live set (R13/R14/R16 post-mortems).
// ---------------------------------------------------------------------------
__global__ __launch_bounds__(64, 3)
void flash_bf16(const ushort_t* __restrict__ Q, const ushort_t* __restrict__ Kl,
                const ushort_t* __restrict__ Vl, ushort_t* __restrict__ attnb)
{
    __shared__ ushort_t Ps[2][2][16 * 68];     // [parity][qgroup]
    const int L = threadIdx.x;                 // 0..63
    const int c = L & 15, g = L >> 4;
    const int bid = blockIdx.x;
    const int slot = bid >> 3;                 // 0..383 within XCD
    const int bh = (bid & 7) * 12 + (slot >> 5);
    const int q0 = (slot & 31) * 32;
    const float SC2 = 0.05205954985329743f;    // 768^-0.5 * log2(e)

    const ushort_t* Qp = Q + ((size_t)bh * 1024 + q0 + c) * 64 + g * 8;
    bf16x8 qf[2][2];
    qf[0][0] = *(const bf16x8*)Qp;
    qf[0][1] = *(const bf16x8*)(Qp + 32);
    qf[1][0] = *(const bf16x8*)(Qp + 16 * 64);
    qf[1][1] = *(const bf16x8*)(Qp + 16 * 64 + 32);

    const ushort_t* Kb = Kl + (size_t)bh * 65536 + (size_t)L * 8;
    const ushort_t* Vb = Vl + (size_t)bh * 65536 + (size_t)L * 8;

    f32x4 o[2][4];
#pragma unroll
    for (int w = 0; w < 2; ++w)
#pragma unroll
        for (int ht = 0; ht < 4; ++ht) o[w][ht] = (f32x4){0.f, 0.f, 0.f, 0.f};
    float ls[2] = {0.f, 0.f};

    bf16x8 kf0[4], kf1[4];
#pragma unroll
    for (int ct = 0; ct < 4; ++ct) {
        kf0[ct] = *(const bf16x8*)(Kb + (size_t)(ct * 2 + 0) * 512);
        kf1[ct] = *(const bf16x8*)(Kb + (size_t)(ct * 2 + 1) * 512);
    }

    for (int T0 = 0; T0 < 16; T0 += 2) {
#pragma unroll
        for (int p = 0; p < 2; ++p) {
            const int T = T0 + p;
            bf16x8 vf0[4], vf1[4];
#pragma unroll
            for (int ht = 0; ht < 4; ++ht) {
                const ushort_t* vp = Vb + (size_t)((ht * 16 + T) * 2) * 512;
                vf0[ht] = *(const bf16x8*)vp;
                vf1[ht] = *(const bf16x8*)(vp + 512);
            }
            f32x4 s[2][4];
#pragma unroll
            for (int w = 0; w < 2; ++w)
#pragma unroll
                for (int ct = 0; ct < 4; ++ct) {
                    f32x4 zz = (f32x4){0.f, 0.f, 0.f, 0.f};
                    zz = __builtin_amdgcn_mfma_f32_16x16x32_bf16(kf0[ct], qf[w][0], zz, 0, 0, 0);
                    zz = __builtin_amdgcn_mfma_f32_16x16x32_bf16(kf1[ct], qf[w][1], zz, 0, 0, 0);
                    s[w][ct] = zz;
                }
            const int Tn = (T < 15) ? T + 1 : 15;
#pragma unroll
            for (int ct = 0; ct < 4; ++ct) {
                const ushort_t* kp = Kb + (size_t)((Tn * 4 + ct) * 2) * 512;
                kf0[ct] = *(const bf16x8*)kp;
                kf1[ct] = *(const bf16x8*)(kp + 512);
            }
#pragma unroll
            for (int w = 0; w < 2; ++w) {
#pragma unroll
                for (int ct = 0; ct < 4; ++ct) {
                    float pv[4];
#pragma unroll
                    for (int r = 0; r < 4; ++r)
                        pv[r] = __builtin_amdgcn_exp2f(s[w][ct][r] * SC2);
                    ls[w] += (pv[0] + pv[1]) + (pv[2] + pv[3]);
                    const unsigned w01 = __builtin_amdgcn_perm(
                        __float_as_uint(pv[1]), __float_as_uint(pv[0]), 0x07060302u);
                    const unsigned w23 = __builtin_amdgcn_perm(
                        __float_as_uint(pv[3]), __float_as_uint(pv[2]), 0x07060302u);
                    *(u32x2*)&Ps[p][w][c * 68 + ct * 16 + g * 4] = (u32x2){w01, w23};
                }
            }
#pragma unroll
            for (int w = 0; w < 2; ++w) {
                const int pb = c * 68 + g * 8;
                const u32x4 pa  = *(const u32x4*)&Ps[p][w][pb];
                const u32x4 pbv = *(const u32x4*)&Ps[p][w][pb + 32];
                const bf16x8 pf0 = __builtin_bit_cast(bf16x8, pa);
                const bf16x8 pf1 = __builtin_bit_cast(bf16x8, pbv);
#pragma unroll
                for (int ht = 0; ht < 4; ++ht) {
                    o[w][ht] = __builtin_amdgcn_mfma_f32_16x16x32_bf16(vf0[ht], pf0, o[w][ht], 0, 0, 0);
                    o[w][ht] = __builtin_amdgcn_mfma_f32_16x16x32_bf16(vf1[ht], pf1, o[w][ht], 0, 0, 0);
                }
            }
        }
    }

    const int b = bh / 12, h = bh % 12;
#pragma unroll
    for (int w = 0; w < 2; ++w) {
        float l = ls[w];
        l += __shfl_xor(l, 16);
        l += __shfl_xor(l, 32);
        const float inv = 1.f / l;
#pragma unroll
        for (int ht = 0; ht < 4; ++ht) {
            const unsigned w0 = pk16(f2bf(o[w][ht][0] * inv), f2bf(o[w][ht][1] * inv));
            const unsigned w1 = pk16(f2bf(o[w][ht][2] * inv), f2bf(o[w][ht][3] * inv));
            *(u32x2*)&Ps[0][w][c * 68 + ht * 16 + g * 4] = (u32x2){w0, w1};
        }
#pragma unroll
        for (int e = 0; e < 2; ++e) {
            const int row = e * 8 + (L >> 3);
            const int ch  = L & 7;
            const int si  = row * 68 + ch * 8;
            const u32x2 t0 = *(const u32x2*)&Ps[0][w][si];
            const u32x2 t1 = *(const u32x2*)&Ps[0][w][si + 4];
            *(u32x4*)&attnb[((size_t)(b * 1024 + q0 + w * 16 + row)) * 768 + h * 64 + ch * 8]
                = (u32x4){t0.x, t0.y, t1.x, t1.y};
        }
    }
}

extern "C" void kernel_launch(void* const* d_in, const int* in_sizes, int n_in,
                              void* d_out, int out_size, void* d_ws, size_t ws_size,
                              hipStream_t stream)
{
    const float* x  = (const float*)d_in[0];
    const float* Wq = (const float*)d_in[1];
    const float* bq = (const float*)d_in[2];
    const float* Wk = (const float*)d_in[3];
    const float* bk = (const float*)d_in[4];
    const float* Wv = (const float*)d_in[5];
    const float* bv = (const float*)d_in[6];
    const float* Wo = (const float*)d_in[7];
    const float* bo = (const float*)d_in[8];
    float* out = (float*)d_out;

    char* ws = (char*)d_ws;
    ushort_t* xb    = (ushort_t*)(ws);
    ushort_t* wqb   = (ushort_t*)(ws + 12582912);
    ushort_t* wkb   = (ushort_t*)(ws + 12582912 + 1179648);
    ushort_t* wvb   = (ushort_t*)(ws + 12582912 + 2359296);
    ushort_t* wob   = (ushort_t*)(ws + 12582912 + 3538944);
    ushort_t* Qh    = (ushort_t*)(ws + 17301504);
    ushort_t* Kl    = (ushort_t*)(ws + 29884416);
    ushort_t* Vl    = (ushort_t*)(ws + 42467328);
    ushort_t* attnb = (ushort_t*)(ws + 55050240);

    cast_all<<<dim3(4224), 256, 0, stream>>>(x, Wq, Wk, Wv, Wo,
                                             xb, wqb, wkb, wvb, wob);
    gemm_qkv<<<dim3(6, 128), 256, 0, stream>>>(xb, wqb, wkb, wvb,
                                               bq, bk, bv, Qh, Kl, Vl);
    flash_bf16<<<dim3(3072), 64, 0, stream>>>(Qh, Kl, Vl, attnb);
    gemm_outp<<<dim3(6, 128), 256, 0, stream>>>(attnb, wob, bo, out);
}

// Round 8
// 183.076 us; speedup vs baseline: 1.0157x; 1.0157x over previous
//
#include <hip/hip_runtime.h>
#include <math.h>

// Round 20: barrier-free GEMMs via frag-linear everything.
// R15/R16/R19 pipeline tweaks were flat: with 3 independent blocks/CU,
// barrier drains are already hidden by other blocks. So remove the LDS
// staging path itself: cast writes xb FRAG-LINEAR (identical tile
// relayout as W); gemm_qkv/gemm_outp read A-frags direct from global
// with in-place prefetch (the proven wf pattern) -> zero barriers, zero
// LDS in the K-loops. flash writes attnb frag-linear in its epilogue
// (same byte count) so outp needs no staging either. Flash main body
// byte-identical to R18 (43us proven; XCD swizzle kept; no setprio, no
// launch-bound tightening -- R13/R14/R16 spills).

typedef __bf16 bf16x8 __attribute__((ext_vector_type(8)));
typedef float  f32x4  __attribute__((ext_vector_type(4)));
typedef unsigned u32x2 __attribute__((ext_vector_type(2)));
typedef unsigned u32x4 __attribute__((ext_vector_type(4)));
typedef unsigned short ushort_t;

__device__ __forceinline__ unsigned short f2bf(float f) {
    unsigned u = __float_as_uint(f);
    u += 0x7fffu + ((u >> 16) & 1u);          // round-to-nearest-even
    return (unsigned short)(u >> 16);
}
__device__ __forceinline__ unsigned pk16(unsigned short lo, unsigned short hi) {
    return (unsigned)lo | ((unsigned)hi << 16);
}

// ---------------------------------------------------------------------------
// cast (1D grid, 4224 blocks, 4 tiles/block): everything frag-linear.
// Tile (t,kb) of source S holds S[t*16+c][kb*32+g*8..+7] at
// ((t*24+kb)*64 + L)*8. Tiles 0..12287 = x->xb; then 4x1152 for weights.
// ---------------------------------------------------------------------------
__global__ __launch_bounds__(256)
void cast_all(const float* __restrict__ x,
              const float* __restrict__ w0, const float* __restrict__ w1,
              const float* __restrict__ w2, const float* __restrict__ w3,
              ushort_t* __restrict__ xb, ushort_t* __restrict__ wb0,
              ushort_t* __restrict__ wb1, ushort_t* __restrict__ wb2,
              ushort_t* __restrict__ wb3)
{
    const int wt0 = blockIdx.x * 4 + (threadIdx.x >> 6);
    const int L = threadIdx.x & 63, c = L & 15, g = L >> 4;
    const float* s; ushort_t* d; int tile;
    if (wt0 < 12288) {                 // x: 512 t-tiles x 24 kb
        s = x; d = xb; tile = wt0;
    } else {
        const int wt = wt0 - 12288;    // weights: 48 t-tiles x 24 kb each
        const int wsel = wt / 1152; tile = wt % 1152;
        switch (wsel) {
            case 0:  s = w0; d = wb0; break;
            case 1:  s = w1; d = wb1; break;
            case 2:  s = w2; d = wb2; break;
            default: s = w3; d = wb3; break;
        }
    }
    const int t = tile / 24, kb = tile % 24;
    const float* sp = s + (size_t)(t * 16 + c) * 768 + kb * 32 + g * 8;
    const float4 f0 = *(const float4*)sp;
    const float4 f1 = *(const float4*)(sp + 4);
    ushort4 p0, p1;
    p0.x = f2bf(f0.x); p0.y = f2bf(f0.y); p0.z = f2bf(f0.z); p0.w = f2bf(f0.w);
    p1.x = f2bf(f1.x); p1.y = f2bf(f1.y); p1.z = f2bf(f1.z); p1.w = f2bf(f1.w);
    ushort_t* dp = d + ((size_t)tile * 64 + L) * 8;
    *(ushort4*)dp       = p0;
    *(ushort4*)(dp + 4) = p1;
}

// ---------------------------------------------------------------------------
// Z-fused QKV GEMM, barrier-free: A and W frags both direct from
// frag-linear global with in-place prefetch. Block = 64m x 128n, 4
// waves. LDS only for per-wave-private epilogue scratch (no syncs).
// ---------------------------------------------------------------------------
__global__ __launch_bounds__(256, 3)
void gemm_qkv(const ushort_t* __restrict__ xb,
              const ushort_t* __restrict__ wqb, const ushort_t* __restrict__ wkb,
              const ushort_t* __restrict__ wvb,
              const float* __restrict__ bq, const float* __restrict__ bk,
              const float* __restrict__ bv,
              ushort_t* __restrict__ Qh, ushort_t* __restrict__ Kl,
              ushort_t* __restrict__ Vl)
{
    __shared__ ushort_t smem[9216];      // epilogue scratch 4x2304, per-wave
    const int tid = threadIdx.x, L = tid & 63, wv = tid >> 6;
    const int c = L & 15, g = L >> 4;
    const int n0 = blockIdx.x * 128, m0 = blockIdx.y * 64;

    // A frag tiles t = by*4 + i; af[i] at ap + i*12288 + kb*512
    const ushort_t* ap = xb + (size_t)(blockIdx.y * 4) * 24 * 512 + (size_t)L * 8;
    // W frag tiles t = bx*8 + wv*2 + j
    const size_t wbase = ((size_t)(blockIdx.x * 8 + wv * 2) * 24 * 64 + L) * 8;
    const ushort_t* wqp = wqb + wbase;
    const ushort_t* wkp = wkb + wbase;
    const ushort_t* wvp = wvb + wbase;
    // j/i tile stride = 24*64*8 = 12288 shorts; kb stride = 512 shorts

    f32x4 acc[3][4][2];
#pragma unroll
    for (int z = 0; z < 3; ++z)
#pragma unroll
        for (int i = 0; i < 4; ++i)
#pragma unroll
            for (int j = 0; j < 2; ++j) acc[z][i][j] = (f32x4){0.f, 0.f, 0.f, 0.f};

    bf16x8 af[4], wf[3][2];
#pragma unroll
    for (int i = 0; i < 4; ++i) af[i] = *(const bf16x8*)(ap + i * 12288);
#pragma unroll
    for (int j = 0; j < 2; ++j) {
        wf[0][j] = *(const bf16x8*)(wqp + j * 12288);
        wf[1][j] = *(const bf16x8*)(wkp + j * 12288);
        wf[2][j] = *(const bf16x8*)(wvp + j * 12288);
    }

    for (int kb = 0; kb < 24; ++kb) {
#pragma unroll
        for (int z = 0; z < 3; ++z)
#pragma unroll
            for (int i = 0; i < 4; ++i)
#pragma unroll
                for (int j = 0; j < 2; ++j)
                    acc[z][i][j] = __builtin_amdgcn_mfma_f32_16x16x32_bf16(
                        af[i], wf[z][j], acc[z][i][j], 0, 0, 0);
        const int kn = (kb < 23) ? kb + 1 : 23;
#pragma unroll
        for (int i = 0; i < 4; ++i)
            af[i] = *(const bf16x8*)(ap + i * 12288 + kn * 512);
#pragma unroll
        for (int j = 0; j < 2; ++j) {
            wf[0][j] = *(const bf16x8*)(wqp + j * 12288 + kn * 512);
            wf[1][j] = *(const bf16x8*)(wkp + j * 12288 + kn * 512);
            wf[2][j] = *(const bf16x8*)(wvp + j * 12288 + kn * 512);
        }
    }

    // ---------------- epilogues (per-wave private strips, no syncs) -------
    const int b  = m0 >> 10, nb = m0 & 1023;
    const int hcol = n0 + wv * 32;
    const int h = hcol >> 6, uh = (hcol >> 5) & 1;
    const int bh = b * 12 + h;
    ushort_t* scr = smem + wv * 2304;

    float bias2[3][2];
#pragma unroll
    for (int j = 0; j < 2; ++j) {
        bias2[0][j] = bq[hcol + j * 16 + c];
        bias2[1][j] = bk[hcol + j * 16 + c];
        bias2[2][j] = bv[hcol + j * 16 + c];
    }

    // z=0: Q plain [bh][token][hd64]; token-major strip [64][36]
#pragma unroll
    for (int i = 0; i < 4; ++i)
#pragma unroll
        for (int j = 0; j < 2; ++j)
#pragma unroll
            for (int r = 0; r < 4; ++r)
                scr[(i * 16 + g * 4 + r) * 36 + j * 16 + c] =
                    f2bf(acc[0][i][j][r] + bias2[0][j]);
#pragma unroll
    for (int e = 0; e < 4; ++e) {
        const int slot = e * 64 + L;
        const int row = slot >> 2, ch = slot & 3;
        const u32x4 v = *(const u32x4*)&scr[row * 36 + ch * 8];
        *(u32x4*)&Qh[((size_t)bh * 1024 + nb + row) * 64 + uh * 32 + ch * 8] = v;
    }

    // z=1: K frag-linear; token-major strip again
#pragma unroll
    for (int i = 0; i < 4; ++i)
#pragma unroll
        for (int j = 0; j < 2; ++j)
#pragma unroll
            for (int r = 0; r < 4; ++r)
                scr[(i * 16 + g * 4 + r) * 36 + j * 16 + c] =
                    f2bf(acc[1][i][j][r] + bias2[1][j]);
#pragma unroll
    for (int tau = 0; tau < 4; ++tau) {
        const u32x4 v = *(const u32x4*)&scr[(tau * 16 + c) * 36 + g * 8];
        *(u32x4*)&Kl[(((size_t)bh * 64 + (nb >> 4) + tau) * 2 + uh) * 512
                     + (size_t)L * 8] = v;
    }

    // z=2: V frag-linear; hd-major strip [32][68]
#pragma unroll
    for (int i = 0; i < 4; ++i)
#pragma unroll
        for (int j = 0; j < 2; ++j)
#pragma unroll
            for (int r = 0; r < 4; ++r)
                scr[(j * 16 + c) * 68 + i * 16 + g * 4 + r] =
                    f2bf(acc[2][i][j][r] + bias2[2][j]);
    const int T = nb >> 6;
#pragma unroll
    for (int t = 0; t < 4; ++t) {
        const int htl = t >> 1, u = t & 1;
        const u32x4 v = *(const u32x4*)&scr[(htl * 16 + c) * 68 + u * 32 + g * 8];
        *(u32x4*)&Vl[((((size_t)bh * 4 + uh * 2 + htl) * 16 + T) * 2 + u) * 512
                     + (size_t)L * 8] = v;
    }
}

// ---------------------------------------------------------------------------
// Out-proj GEMM, fully LDS-free/barrier-free: A (frag-linear attnb from
// flash) and W both direct from global. 64m x 128n, grid 6x128.
// ---------------------------------------------------------------------------
__global__ __launch_bounds__(256, 3)
void gemm_outp(const ushort_t* __restrict__ attnb, const ushort_t* __restrict__ wob,
               const float* __restrict__ bo, float* __restrict__ out)
{
    const int tid = threadIdx.x, L = tid & 63, wv = tid >> 6;
    const int c = L & 15, g = L >> 4;
    const int n0 = blockIdx.x * 128, m0 = blockIdx.y * 64;

    const ushort_t* ap = attnb + (size_t)(blockIdx.y * 4) * 24 * 512 + (size_t)L * 8;
    const size_t wbase = ((size_t)(blockIdx.x * 8 + wv * 2) * 24 * 64 + L) * 8;
    const ushort_t* wop = wob + wbase;

    f32x4 acc[4][2];
#pragma unroll
    for (int i = 0; i < 4; ++i)
#pragma unroll
        for (int j = 0; j < 2; ++j) acc[i][j] = (f32x4){0.f, 0.f, 0.f, 0.f};

    bf16x8 af[4], wf[2];
#pragma unroll
    for (int i = 0; i < 4; ++i) af[i] = *(const bf16x8*)(ap + i * 12288);
#pragma unroll
    for (int j = 0; j < 2; ++j) wf[j] = *(const bf16x8*)(wop + j * 12288);

    for (int kb = 0; kb < 24; ++kb) {
#pragma unroll
        for (int i = 0; i < 4; ++i)
#pragma unroll
            for (int j = 0; j < 2; ++j)
                acc[i][j] = __builtin_amdgcn_mfma_f32_16x16x32_bf16(
                    af[i], wf[j], acc[i][j], 0, 0, 0);
        const int kn = (kb < 23) ? kb + 1 : 23;
#pragma unroll
        for (int i = 0; i < 4; ++i)
            af[i] = *(const bf16x8*)(ap + i * 12288 + kn * 512);
#pragma unroll
        for (int j = 0; j < 2; ++j)
            wf[j] = *(const bf16x8*)(wop + j * 12288 + kn * 512);
    }

#pragma unroll
    for (int i = 0; i < 4; ++i) {
        const int row = m0 + i * 16 + g * 4;
#pragma unroll
        for (int j = 0; j < 2; ++j) {
            const int col = n0 + wv * 32 + j * 16 + c;
            const float bsvo = bo[col];
#pragma unroll
            for (int r = 0; r < 4; ++r)
                out[(size_t)(row + r) * 768 + col] = acc[i][j][r] + bsvo;
        }
    }
}

// ---------------------------------------------------------------------------
// Flash (R12 body + XCD swizzle; frag-linear attnb epilogue): S^T =
// K.Q^T, fixed-max softmax, 1 wave/block, 32 q-rows, parity P-strips,
// in-place K prefetch, bare v_exp_f32. 1D grid 3072: xcd = bid&7 owns
// 12 complete bh. Do NOT tighten launch bounds / insert setprio (spills,
// R13/R14/R16).
// ---------------------------------------------------------------------------
__global__ __launch_bounds__(64, 3)
void flash_bf16(const ushort_t* __restrict__ Q, const ushort_t* __restrict__ Kl,
                const ushort_t* __restrict__ Vl, ushort_t* __restrict__ attnb)
{
    __shared__ ushort_t Ps[2][2][16 * 68];     // [parity][qgroup]
    const int L = threadIdx.x;                 // 0..63
    const int c = L & 15, g = L >> 4;
    const int bid = blockIdx.x;
    const int slot = bid >> 3;                 // 0..383 within XCD
    const int bh = (bid & 7) * 12 + (slot >> 5);
    const int q0 = (slot & 31) * 32;
    const float SC2 = 0.05205954985329743f;    // 768^-0.5 * log2(e)

    const ushort_t* Qp = Q + ((size_t)bh * 1024 + q0 + c) * 64 + g * 8;
    bf16x8 qf[2][2];
    qf[0][0] = *(const bf16x8*)Qp;
    qf[0][1] = *(const bf16x8*)(Qp + 32);
    qf[1][0] = *(const bf16x8*)(Qp + 16 * 64);
    qf[1][1] = *(const bf16x8*)(Qp + 16 * 64 + 32);

    const ushort_t* Kb = Kl + (size_t)bh * 65536 + (size_t)L * 8;
    const ushort_t* Vb = Vl + (size_t)bh * 65536 + (size_t)L * 8;

    f32x4 o[2][4];
#pragma unroll
    for (int w = 0; w < 2; ++w)
#pragma unroll
        for (int ht = 0; ht < 4; ++ht) o[w][ht] = (f32x4){0.f, 0.f, 0.f, 0.f};
    float ls[2] = {0.f, 0.f};

    bf16x8 kf0[4], kf1[4];
#pragma unroll
    for (int ct = 0; ct < 4; ++ct) {
        kf0[ct] = *(const bf16x8*)(Kb + (size_t)(ct * 2 + 0) * 512);
        kf1[ct] = *(const bf16x8*)(Kb + (size_t)(ct * 2 + 1) * 512);
    }

    for (int T0 = 0; T0 < 16; T0 += 2) {
#pragma unroll
        for (int p = 0; p < 2; ++p) {
            const int T = T0 + p;
            bf16x8 vf0[4], vf1[4];
#pragma unroll
            for (int ht = 0; ht < 4; ++ht) {
                const ushort_t* vp = Vb + (size_t)((ht * 16 + T) * 2) * 512;
                vf0[ht] = *(const bf16x8*)vp;
                vf1[ht] = *(const bf16x8*)(vp + 512);
            }
            f32x4 s[2][4];
#pragma unroll
            for (int w = 0; w < 2; ++w)
#pragma unroll
                for (int ct = 0; ct < 4; ++ct) {
                    f32x4 zz = (f32x4){0.f, 0.f, 0.f, 0.f};
                    zz = __builtin_amdgcn_mfma_f32_16x16x32_bf16(kf0[ct], qf[w][0], zz, 0, 0, 0);
                    zz = __builtin_amdgcn_mfma_f32_16x16x32_bf16(kf1[ct], qf[w][1], zz, 0, 0, 0);
                    s[w][ct] = zz;
                }
            const int Tn = (T < 15) ? T + 1 : 15;
#pragma unroll
            for (int ct = 0; ct < 4; ++ct) {
                const ushort_t* kp = Kb + (size_t)((Tn * 4 + ct) * 2) * 512;
                kf0[ct] = *(const bf16x8*)kp;
                kf1[ct] = *(const bf16x8*)(kp + 512);
            }
#pragma unroll
            for (int w = 0; w < 2; ++w) {
#pragma unroll
                for (int ct = 0; ct < 4; ++ct) {
                    float pv[4];
#pragma unroll
                    for (int r = 0; r < 4; ++r)
                        pv[r] = __builtin_amdgcn_exp2f(s[w][ct][r] * SC2);
                    ls[w] += (pv[0] + pv[1]) + (pv[2] + pv[3]);
                    const unsigned w01 = __builtin_amdgcn_perm(
                        __float_as_uint(pv[1]), __float_as_uint(pv[0]), 0x07060302u);
                    const unsigned w23 = __builtin_amdgcn_perm(
                        __float_as_uint(pv[3]), __float_as_uint(pv[2]), 0x07060302u);
                    *(u32x2*)&Ps[p][w][c * 68 + ct * 16 + g * 4] = (u32x2){w01, w23};
                }
            }
#pragma unroll
            for (int w = 0; w < 2; ++w) {
                const int pb = c * 68 + g * 8;
                const u32x4 pa  = *(const u32x4*)&Ps[p][w][pb];
                const u32x4 pbv = *(const u32x4*)&Ps[p][w][pb + 32];
                const bf16x8 pf0 = __builtin_bit_cast(bf16x8, pa);
                const bf16x8 pf1 = __builtin_bit_cast(bf16x8, pbv);
#pragma unroll
                for (int ht = 0; ht < 4; ++ht) {
                    o[w][ht] = __builtin_amdgcn_mfma_f32_16x16x32_bf16(vf0[ht], pf0, o[w][ht], 0, 0, 0);
                    o[w][ht] = __builtin_amdgcn_mfma_f32_16x16x32_bf16(vf1[ht], pf1, o[w][ht], 0, 0, 0);
                }
            }
        }
    }

    const int b = bh / 12, h = bh % 12;
    const int tB = b * 64 + (q0 >> 4);         // token-tile base (w adds +w)
#pragma unroll
    for (int w = 0; w < 2; ++w) {
        float l = ls[w];
        l += __shfl_xor(l, 16);
        l += __shfl_xor(l, 32);
        const float inv = 1.f / l;
#pragma unroll
        for (int ht = 0; ht < 4; ++ht) {
            const unsigned w0 = pk16(f2bf(o[w][ht][0] * inv), f2bf(o[w][ht][1] * inv));
            const unsigned w1 = pk16(f2bf(o[w][ht][2] * inv), f2bf(o[w][ht][3] * inv));
            *(u32x2*)&Ps[0][w][c * 68 + ht * 16 + g * 4] = (u32x2){w0, w1};
        }
        // frag-linear store: tile t = tB + w, kb = h*2 + kbi; lane L holds
        // row c, hd kbi*32 + g*8..+7 (read from [qrow][hd] strip).
#pragma unroll
        for (int kbi = 0; kbi < 2; ++kbi) {
            const u32x4 v = *(const u32x4*)&Ps[0][w][c * 68 + kbi * 32 + g * 8];
            *(u32x4*)&attnb[(((size_t)(tB + w) * 24 + h * 2 + kbi) * 64 + L) * 8] = v;
        }
    }
}

extern "C" void kernel_launch(void* const* d_in, const int* in_sizes, int n_in,
                              void* d_out, int out_size, void* d_ws, size_t ws_size,
                              hipStream_t stream)
{
    const float* x  = (const float*)d_in[0];
    const float* Wq = (const float*)d_in[1];
    const float* bq = (const float*)d_in[2];
    const float* Wk = (const float*)d_in[3];
    const float* bk = (const float*)d_in[4];
    const float* Wv = (const float*)d_in[5];
    const float* bv = (const float*)d_in[6];
    const float* Wo = (const float*)d_in[7];
    const float* bo = (const float*)d_in[8];
    float* out = (float*)d_out;

    char* ws = (char*)d_ws;
    ushort_t* xb    = (ushort_t*)(ws);
    ushort_t* wqb   = (ushort_t*)(ws + 12582912);
    ushort_t* wkb   = (ushort_t*)(ws + 12582912 + 1179648);
    ushort_t* wvb   = (ushort_t*)(ws + 12582912 + 2359296);
    ushort_t* wob   = (ushort_t*)(ws + 12582912 + 3538944);
    ushort_t* Qh    = (ushort_t*)(ws + 17301504);
    ushort_t* Kl    = (ushort_t*)(ws + 29884416);
    ushort_t* Vl    = (ushort_t*)(ws + 42467328);
    ushort_t* attnb = (ushort_t*)(ws + 55050240);

    cast_all<<<dim3(4224), 256, 0, stream>>>(x, Wq, Wk, Wv, Wo,
                                             xb, wqb, wkb, wvb, wob);
    gemm_qkv<<<dim3(6, 128), 256, 0, stream>>>(xb, wqb, wkb, wvb,
                                               bq, bk, bv, Qh, Kl, Vl);
    flash_bf16<<<dim3(3072), 64, 0, stream>>>(Qh, Kl, Vl, attnb);
    gemm_outp<<<dim3(6, 128), 256, 0, stream>>>(attnb, wob, bo, out);
}